// Round 17
// baseline (139.972 us; speedup 1.0000x reference)
//
#include <hip/hip_runtime.h>
#include <stdint.h>

#define KNN 16
#define CLEN 4
#define NB 4
#define NP 8192
#define G 16
#define NC (G * G * G)
#define GLO -4.5f
#define INVW 1.7777777777777777f
#define CSPLIT 8
#define CHUNK (NP / CSPLIT)   // 1024 candidates per chunk-thread
#define QPB 64                // queries per block
#define TPB (QPB * CSPLIT)    // 512 threads
#define SDEPTH 12             // per-lane LDS pending stack depth
#define TWIN 128              // threshold window (16th-smallest of 128)

// FP-rounding sequence verified bit-exact vs reference (rounds 1-16):
//   sq = (x*x + y*y) + z*z (no fma), dot = fma chain, d2 = fma(-2,dot,sqn+sqm)

__device__ __forceinline__ unsigned sp3(unsigned v) {
  v = (v | (v << 16)) & 0x030000FFu;
  v = (v | (v << 8)) & 0x0300F00Fu;
  v = (v | (v << 4)) & 0x030C30C3u;
  v = (v | (v << 2)) & 0x09249249u;
  return v;
}
__device__ __forceinline__ int morton3(int cx, int cy, int cz) {
  return (int)(sp3((unsigned)cx) | (sp3((unsigned)cy) << 1) | (sp3((unsigned)cz) << 2));
}
__device__ __forceinline__ int cell1(float v) {
  int c = (int)floorf((v - GLO) * INVW);
  return min(G - 1, max(0, c));
}

__global__ void bin_kernel(const float* __restrict__ xyz, int* __restrict__ cellid,
                           int* __restrict__ hist) {
  int t = blockIdx.x * blockDim.x + threadIdx.x;
  if (t >= NB * NP) return;
  int b = t >> 13;
  int m = morton3(cell1(xyz[t * 3 + 0]), cell1(xyz[t * 3 + 1]), cell1(xyz[t * 3 + 2]));
  cellid[t] = m;
  atomicAdd(&hist[b * NC + m], 1);
}

__global__ __launch_bounds__(1024) void scan_kernel(const int* __restrict__ hist,
                                                    int* __restrict__ offs) {
  __shared__ int s[1024];
  int b = blockIdx.x, t = threadIdx.x;
  int base = b * NC + t * 4;
  int v0 = hist[base + 0], v1 = hist[base + 1], v2 = hist[base + 2], v3 = hist[base + 3];
  int sum = v0 + v1 + v2 + v3;
  s[t] = sum;
  __syncthreads();
  for (int d = 1; d < 1024; d <<= 1) {
    int x = 0;
    if (t >= d) x = s[t - d];
    __syncthreads();
    if (t >= d) s[t] += x;
    __syncthreads();
  }
  int run = s[t] - sum;  // exclusive
  offs[base + 0] = run; run += v0;
  offs[base + 1] = run; run += v1;
  offs[base + 2] = run; run += v2;
  offs[base + 3] = run;
}

// Writes BOTH the Morton-sorted array (for threshold windows) and the
// natural-order array (for the balanced brute-force scan).
__global__ void scatter_kernel(const float* __restrict__ xyz, const int* __restrict__ cellid,
                               const int* __restrict__ offs, int* __restrict__ cursor,
                               float4* __restrict__ scand, int* __restrict__ sidx,
                               float4* __restrict__ cand) {
#pragma clang fp contract(off)
  int t = blockIdx.x * blockDim.x + threadIdx.x;
  if (t >= NB * NP) return;
  int b = t >> 13, n = t & (NP - 1);
  float x = xyz[t * 3 + 0], y = xyz[t * 3 + 1], z = xyz[t * 3 + 2];
  float sq = (x * x + y * y) + z * z;   // verified non-fma sequence
  cand[t] = make_float4(x, y, z, sq);
  int m = cellid[t];
  int pos = offs[b * NC + m] + atomicAdd(&cursor[b * NC + m], 1);
  scand[b * NP + pos] = make_float4(x, y, z, sq);
  sidx[b * NP + pos] = n;
}

// Per-query selection threshold = 16th-SMALLEST distance over a 128-point
// Morton window. 16th-of-any-subset >= global 16th-smallest -> exact-
// conservative; larger window = tighter threshold = fewer scan accepts.
__global__ void thresh_kernel(const float4* __restrict__ scand, const int* __restrict__ sidx,
                              float* __restrict__ thr) {
#pragma clang fp contract(off)
  int s = blockIdx.x * blockDim.x + threadIdx.x;
  if (s >= NB * NP) return;
  int b = s >> 13;
  int bbase = b * NP;
  float4 qd = scand[s];
  int w0 = s - (TWIN / 2);
  if (w0 < bbase) w0 = bbase;
  if (w0 > bbase + NP - TWIN) w0 = bbase + NP - TWIN;
  float dist[KNN];
#pragma unroll
  for (int j = 0; j < KNN; ++j) dist[j] = __builtin_inff();
#pragma unroll 1
  for (int i = 0; i < TWIN; i += 8) {
    float4 c0 = scand[w0 + i + 0];
    float4 c1 = scand[w0 + i + 1];
    float4 c2 = scand[w0 + i + 2];
    float4 c3 = scand[w0 + i + 3];
    float4 c4 = scand[w0 + i + 4];
    float4 c5 = scand[w0 + i + 5];
    float4 c6 = scand[w0 + i + 6];
    float4 c7 = scand[w0 + i + 7];
#define TPROC(cc)                                                   \
    do {                                                            \
      float p0 = qd.x * (cc).x;                                     \
      float dot = fmaf(qd.z, (cc).z, fmaf(qd.y, (cc).y, p0));       \
      float d2 = fmaf(-2.0f, dot, qd.w + (cc).w);                   \
      _Pragma("unroll")                                             \
      for (int j = KNN - 1; j >= 1; --j)                            \
        dist[j] = __builtin_amdgcn_fmed3f(dist[j - 1], dist[j], d2);\
      dist[0] = fminf(dist[0], d2);                                 \
    } while (0)
    TPROC(c0); TPROC(c1); TPROC(c2); TPROC(c3);
    TPROC(c4); TPROC(c5); TPROC(c6); TPROC(c7);
#undef TPROC
  }
  thr[bbase + sidx[s]] = dist[KNN - 1];
}

// Stable sorted-insert into ascending (dist[], idx[]), med3 encoding
// (verified bit-exact rounds 1-16). Strict > places d after equals;
// candidates arrive in ascending natural index order -> exact top_k ties.
#define INSERT(dv, iv)                                              \
  do {                                                              \
    float _d = (dv); int _i = (iv);                                 \
    bool c[KNN];                                                    \
    _Pragma("unroll")                                               \
    for (int j = 0; j < KNN; ++j) c[j] = dist[j] > _d;              \
    _Pragma("unroll")                                               \
    for (int j = KNN - 1; j >= 1; --j) {                            \
      dist[j] = __builtin_amdgcn_fmed3f(dist[j - 1], dist[j], _d);  \
      idx[j] = c[j - 1] ? idx[j - 1] : (c[j] ? _i : idx[j]);        \
    }                                                               \
    dist[0] = fminf(dist[0], _d);                                   \
    idx[0] = c[0] ? _i : idx[0];                                    \
  } while (0)

// Batched drain, oldest first. dmax tightens but never loosens past the
// seed threshold (list 16th starts at +inf).
#define FLUSH()                                                \
  do {                                                         \
    float2 e[SDEPTH];                                          \
    _Pragma("unroll")                                          \
    for (int j = 0; j < SDEPTH; ++j) e[j] = stk[j * TPB + t];  \
    _Pragma("unroll")                                          \
    for (int j = 0; j < SDEPTH; ++j) {                         \
      if (!__any(j < pc)) break;                               \
      bool act = j < pc;                                       \
      float fd = act ? e[j].x : __builtin_inff();              \
      int fi = __float_as_int(e[j].y);                         \
      INSERT(fd, fi);                                          \
    }                                                          \
    pc = 0;                                                    \
    dmax = fminf(dmax, dist[KNN - 1]);                         \
  } while (0)

// R16 structure (119 us knn, VALUBusy 71%): LDS candidate staging —
//  - one coalesced global load per 64 candidates into a per-wave LDS double
//    buffer, prefetched 2 groups (~2000 cy) ahead
//  - inner loop consumes via broadcast ds_read_b128 (conflict-free)
//  - buffer state in LDS, prefetch in ONE float4 reg -> no spill
__global__ __launch_bounds__(TPB, 4) void knn_kernel(const float4* __restrict__ cand,
                                                     const float* __restrict__ thr,
                                                     int* __restrict__ knn) {
#pragma clang fp contract(off)
  // 64 KB shared: [0,48K) stacks [SDEPTH][TPB] f2; [48K,64K) staging
  // [8 waves][2 bufs][64] float4. Merge phase reuses [0,40K).
  __shared__ __align__(16) char smem[65536];
  float2* stk = (float2*)smem;

  const int t = threadIdx.x;
  const int lane = t & 63;
  const int wid = t >> 6;                    // wave id == chunk id (QPB==64)
  const int bq = blockIdx.x * QPB + lane;
  const int b = bq >> 13;
  const float4 qd = cand[bq];
  const float4* cb = cand + b * NP;

  float dist[KNN];
  int idx[KNN];
#pragma unroll
  for (int j = 0; j < KNN; ++j) { dist[j] = __builtin_inff(); idx[j] = 0; }
  float dmax = thr[bq];   // conservative seed threshold (>= true 16th distance)
  int pc = 0;

  const int m0 = wid * CHUNK;
  float4* sb = ((float4*)(smem + 49152)) + (size_t)wid * 128;  // [2][64]

  // prologue: group 0 -> buf0; prefetch group 1 into r
  float4 r = cb[m0 + lane];
  sb[lane] = r;
  r = cb[m0 + 64 + lane];
  int p = 0;

#pragma unroll 1
  for (int s = 0; s < CHUNK; s += 64) {
    // drain prior staging write (issued a full group ago -> ~free)
    asm volatile("s_waitcnt lgkmcnt(0)" ::: "memory");
    if (s + 64 < CHUNK) {
      sb[(p ^ 1) * 64 + lane] = r;                 // stage next group
      if (s + 128 < CHUNK) r = cb[m0 + s + 128 + lane];  // prefetch next-next
    }
    const float4* cur = sb + p * 64;
#pragma unroll 1
    for (int g = 0; g < 64; g += 8) {
      float4 c0 = cur[g + 0];
      float4 c1 = cur[g + 1];
      float4 c2 = cur[g + 2];
      float4 c3 = cur[g + 3];
      float4 c4 = cur[g + 4];
      float4 c5 = cur[g + 5];
      float4 c6 = cur[g + 6];
      float4 c7 = cur[g + 7];
#define PROC(cc, mm)                                                \
      do {                                                          \
        float p0 = qd.x * (cc).x;                                   \
        float dot = fmaf(qd.z, (cc).z, fmaf(qd.y, (cc).y, p0));     \
        float d2 = fmaf(-2.0f, dot, qd.w + (cc).w);                 \
        if (d2 <= dmax) { /* <= : boundary points admissible */     \
          stk[pc * TPB + t] = make_float2(d2, __int_as_float(mm));  \
          ++pc;                                                     \
        }                                                           \
      } while (0)
      PROC(c0, m0 + s + g + 0);
      PROC(c1, m0 + s + g + 1);
      PROC(c2, m0 + s + g + 2);
      PROC(c3, m0 + s + g + 3);
      PROC(c4, m0 + s + g + 4);
      PROC(c5, m0 + s + g + 5);
      PROC(c6, m0 + s + g + 6);
      PROC(c7, m0 + s + g + 7);
#undef PROC
      // post-flush pc==0; check at >=5 leaves pc<=4; +8 -> pc<=12=SDEPTH
      if (__any(pc >= SDEPTH - 7)) FLUSH();
    }
    p ^= 1;
  }
  FLUSH();

  __syncthreads();  // repurpose smem: transposed lists (conflict-free)
  float2* tl = (float2*)smem;               // [KNN][4*QPB] = 32 KB
  float2* al = (float2*)(smem + 32768);     // [KNN][QPB]   =  8 KB

  // ---- phase A: chunks 0..3 publish, 4-way stable merge -> al ----
  if (wid < 4) {
#pragma unroll
    for (int j = 0; j < KNN; ++j)
      tl[j * (4 * QPB) + t] = make_float2(dist[j], __int_as_float(idx[j]));
  }
  __syncthreads();
  if (t < QPB) {
    int p4[4] = {0, 0, 0, 0};
#pragma unroll 1
    for (int j = 0; j < KNN; ++j) {
      float bd = __builtin_inff();
      int bi = 0, bc = 0;
#pragma unroll
      for (int c = 0; c < 4; ++c) {
        bool v = p4[c] < KNN;
        int pp = v ? p4[c] : 0;
        float2 e = tl[pp * (4 * QPB) + t + c * QPB];
        float hd = v ? e.x : __builtin_inff();
        // strict < keeps the earliest chunk on ties (ascending index ranges)
        if (hd < bd || c == 0) { bd = hd; bi = __float_as_int(e.y); bc = c; }
      }
      al[j * QPB + t] = make_float2(bd, __int_as_float(bi));
#pragma unroll
      for (int c = 0; c < 4; ++c) p4[c] += (bc == c);
    }
  }
  __syncthreads();

  // ---- phase B: chunks 4..7 publish (reuse region), 5-way merge -> out ----
  if (wid >= 4) {
#pragma unroll
    for (int j = 0; j < KNN; ++j)
      tl[j * (4 * QPB) + (t - 4 * QPB)] = make_float2(dist[j], __int_as_float(idx[j]));
  }
  __syncthreads();
  if (t < QPB) {
    int p5[5] = {0, 0, 0, 0, 0};  // 0 = al (chunks 0-3), 1..4 = chunks 4..7
    int* kn = knn + bq * KNN;
#pragma unroll 1
    for (int j = 0; j < KNN; ++j) {
      float bd;
      int bi, bc;
      {
        bool v = p5[0] < KNN;
        int pp = v ? p5[0] : 0;
        float2 e = al[pp * QPB + t];
        bd = v ? e.x : __builtin_inff();
        bi = __float_as_int(e.y);
        bc = 0;
      }
#pragma unroll
      for (int c = 0; c < 4; ++c) {
        bool v = p5[c + 1] < KNN;
        int pp = v ? p5[c + 1] : 0;
        float2 e = tl[pp * (4 * QPB) + t + c * QPB];
        float hd = v ? e.x : __builtin_inff();
        if (hd < bd) { bd = hd; bi = __float_as_int(e.y); bc = c + 1; }
      }
      kn[j] = bi;
#pragma unroll
      for (int c = 0; c < 5; ++c) p5[c] += (bc == c);
    }
  }
}

__global__ void walk_kernel(const int* __restrict__ rand_k, const int* __restrict__ knn,
                            int* __restrict__ out) {
  int t = blockIdx.x * blockDim.x + threadIdx.x;
  if (t >= NB * NP) return;
  int b = t >> 13;
  int n = t & (NP - 1);
  int cur = n;
  int* o = out + t * CLEN;
  o[0] = cur;
#pragma unroll
  for (int l = 0; l < CLEN - 1; ++l) {
    int rk = rand_k[(l * NB + b) * NP + n];
    cur = knn[(b * NP + cur) * KNN + rk];
    o[l + 1] = cur;
  }
}

extern "C" void kernel_launch(void* const* d_in, const int* in_sizes, int n_in,
                              void* d_out, int out_size, void* d_ws, size_t ws_size,
                              hipStream_t stream) {
  const float* xyz = (const float*)d_in[0];
  const int* rand_k = (const int*)d_in[1];
  int* out = (int*)d_out;

  char* w = (char*)d_ws;
  float4* cand  = (float4*)(w);                       // 512 KB natural order
  float4* scand = (float4*)(w + 524288);              // 512 KB Morton-sorted
  int* sidx     = (int*)(w + 1048576);                // 128 KB
  float* thr    = (float*)(w + 1179648);              // 128 KB
  int* knnt     = (int*)(w + 1310720);                // 2 MB
  int* cellid   = (int*)(w + 3407872);                // 128 KB
  int* hist     = (int*)(w + 3538944);                // 64 KB
  int* cursor   = (int*)(w + 3604480);                // 64 KB (adjacent)
  int* offs     = (int*)(w + 3670016);                // 64 KB

  hipMemsetAsync(hist, 0, 131072, stream);  // hist + cursor

  bin_kernel<<<(NB * NP + 255) / 256, 256, 0, stream>>>(xyz, cellid, hist);
  scan_kernel<<<NB, 1024, 0, stream>>>(hist, offs);
  scatter_kernel<<<(NB * NP + 255) / 256, 256, 0, stream>>>(xyz, cellid, offs, cursor,
                                                            scand, sidx, cand);
  thresh_kernel<<<(NB * NP + 255) / 256, 256, 0, stream>>>(scand, sidx, thr);
  knn_kernel<<<(NB * NP) / QPB, TPB, 0, stream>>>(cand, thr, knnt);
  walk_kernel<<<(NB * NP + 255) / 256, 256, 0, stream>>>(rand_k, knnt, out);
}

// Round 18
// 120.160 us; speedup vs baseline: 1.1649x; 1.1649x over previous
//
#include <hip/hip_runtime.h>
#include <stdint.h>

#define KNN 16
#define CLEN 4
#define NB 4
#define NP 8192
#define G 16
#define NC (G * G * G)
#define GLO -4.5f
#define INVW 1.7777777777777777f
#define CSPLIT 8
#define CHUNK (NP / CSPLIT)   // 1024 candidates per chunk-thread
#define QPB 64                // queries per block
#define TPB (QPB * CSPLIT)    // 512 threads
#define SDEPTH 12             // per-lane LDS pending stack depth
#define TWIN 128              // threshold window (16th-smallest of 128)

// FP-rounding sequence verified bit-exact vs reference (rounds 1-17):
//   sq = (x*x + y*y) + z*z (no fma), dot = fma chain, d2 = fma(-2,dot,sqn+sqm)

__device__ __forceinline__ unsigned sp3(unsigned v) {
  v = (v | (v << 16)) & 0x030000FFu;
  v = (v | (v << 8)) & 0x0300F00Fu;
  v = (v | (v << 4)) & 0x030C30C3u;
  v = (v | (v << 2)) & 0x09249249u;
  return v;
}
__device__ __forceinline__ int morton3(int cx, int cy, int cz) {
  return (int)(sp3((unsigned)cx) | (sp3((unsigned)cy) << 1) | (sp3((unsigned)cz) << 2));
}
__device__ __forceinline__ int cell1(float v) {
  int c = (int)floorf((v - GLO) * INVW);
  return min(G - 1, max(0, c));
}

__global__ void bin_kernel(const float* __restrict__ xyz, int* __restrict__ cellid,
                           int* __restrict__ hist) {
  int t = blockIdx.x * blockDim.x + threadIdx.x;
  if (t >= NB * NP) return;
  int b = t >> 13;
  int m = morton3(cell1(xyz[t * 3 + 0]), cell1(xyz[t * 3 + 1]), cell1(xyz[t * 3 + 2]));
  cellid[t] = m;
  atomicAdd(&hist[b * NC + m], 1);
}

__global__ __launch_bounds__(1024) void scan_kernel(const int* __restrict__ hist,
                                                    int* __restrict__ offs) {
  __shared__ int s[1024];
  int b = blockIdx.x, t = threadIdx.x;
  int base = b * NC + t * 4;
  int v0 = hist[base + 0], v1 = hist[base + 1], v2 = hist[base + 2], v3 = hist[base + 3];
  int sum = v0 + v1 + v2 + v3;
  s[t] = sum;
  __syncthreads();
  for (int d = 1; d < 1024; d <<= 1) {
    int x = 0;
    if (t >= d) x = s[t - d];
    __syncthreads();
    if (t >= d) s[t] += x;
    __syncthreads();
  }
  int run = s[t] - sum;  // exclusive
  offs[base + 0] = run; run += v0;
  offs[base + 1] = run; run += v1;
  offs[base + 2] = run; run += v2;
  offs[base + 3] = run;
}

// Writes BOTH the Morton-sorted array (for threshold windows) and the
// natural-order array (for the balanced brute-force scan).
__global__ void scatter_kernel(const float* __restrict__ xyz, const int* __restrict__ cellid,
                               const int* __restrict__ offs, int* __restrict__ cursor,
                               float4* __restrict__ scand, int* __restrict__ sidx,
                               float4* __restrict__ cand) {
#pragma clang fp contract(off)
  int t = blockIdx.x * blockDim.x + threadIdx.x;
  if (t >= NB * NP) return;
  int b = t >> 13, n = t & (NP - 1);
  float x = xyz[t * 3 + 0], y = xyz[t * 3 + 1], z = xyz[t * 3 + 2];
  float sq = (x * x + y * y) + z * z;   // verified non-fma sequence
  cand[t] = make_float4(x, y, z, sq);
  int m = cellid[t];
  int pos = offs[b * NC + m] + atomicAdd(&cursor[b * NC + m], 1);
  scand[b * NP + pos] = make_float4(x, y, z, sq);
  sidx[b * NP + pos] = n;
}

// Per-query selection threshold = 16th-SMALLEST distance over a 128-point
// Morton window. 16th-of-any-subset >= global 16th-smallest -> exact-
// conservative; larger window = tighter threshold = fewer scan accepts.
__global__ void thresh_kernel(const float4* __restrict__ scand, const int* __restrict__ sidx,
                              float* __restrict__ thr) {
#pragma clang fp contract(off)
  int s = blockIdx.x * blockDim.x + threadIdx.x;
  if (s >= NB * NP) return;
  int b = s >> 13;
  int bbase = b * NP;
  float4 qd = scand[s];
  int w0 = s - (TWIN / 2);
  if (w0 < bbase) w0 = bbase;
  if (w0 > bbase + NP - TWIN) w0 = bbase + NP - TWIN;
  float dist[KNN];
#pragma unroll
  for (int j = 0; j < KNN; ++j) dist[j] = __builtin_inff();
#pragma unroll 1
  for (int i = 0; i < TWIN; i += 8) {
    float4 c0 = scand[w0 + i + 0];
    float4 c1 = scand[w0 + i + 1];
    float4 c2 = scand[w0 + i + 2];
    float4 c3 = scand[w0 + i + 3];
    float4 c4 = scand[w0 + i + 4];
    float4 c5 = scand[w0 + i + 5];
    float4 c6 = scand[w0 + i + 6];
    float4 c7 = scand[w0 + i + 7];
#define TPROC(cc)                                                   \
    do {                                                            \
      float p0 = qd.x * (cc).x;                                     \
      float dot = fmaf(qd.z, (cc).z, fmaf(qd.y, (cc).y, p0));       \
      float d2 = fmaf(-2.0f, dot, qd.w + (cc).w);                   \
      _Pragma("unroll")                                             \
      for (int j = KNN - 1; j >= 1; --j)                            \
        dist[j] = __builtin_amdgcn_fmed3f(dist[j - 1], dist[j], d2);\
      dist[0] = fminf(dist[0], d2);                                 \
    } while (0)
    TPROC(c0); TPROC(c1); TPROC(c2); TPROC(c3);
    TPROC(c4); TPROC(c5); TPROC(c6); TPROC(c7);
#undef TPROC
  }
  thr[bbase + sidx[s]] = dist[KNN - 1];
}

// Stable sorted-insert into ascending (dist[], idx[]), med3 encoding
// (verified bit-exact rounds 1-17). Strict > places d after equals;
// candidates arrive in ascending natural index order -> exact top_k ties.
#define INSERT(dv, iv)                                              \
  do {                                                              \
    float _d = (dv); int _i = (iv);                                 \
    bool c[KNN];                                                    \
    _Pragma("unroll")                                               \
    for (int j = 0; j < KNN; ++j) c[j] = dist[j] > _d;              \
    _Pragma("unroll")                                               \
    for (int j = KNN - 1; j >= 1; --j) {                            \
      dist[j] = __builtin_amdgcn_fmed3f(dist[j - 1], dist[j], _d);  \
      idx[j] = c[j - 1] ? idx[j - 1] : (c[j] ? _i : idx[j]);        \
    }                                                               \
    dist[0] = fminf(dist[0], _d);                                   \
    idx[0] = c[0] ? _i : idx[0];                                    \
  } while (0)

// Batched drain, oldest first. dmax tightens but never loosens past the
// seed threshold (list 16th starts at +inf); hb (dot-space threshold base)
// is refreshed whenever dmax changes.
#define FLUSH()                                                \
  do {                                                         \
    float2 e[SDEPTH];                                          \
    _Pragma("unroll")                                          \
    for (int j = 0; j < SDEPTH; ++j) e[j] = stk[j * TPB + t];  \
    _Pragma("unroll")                                          \
    for (int j = 0; j < SDEPTH; ++j) {                         \
      if (!__any(j < pc)) break;                               \
      bool act = j < pc;                                       \
      float fd = act ? e[j].x : __builtin_inff();              \
      int fi = __float_as_int(e[j].y);                         \
      INSERT(fd, fi);                                          \
    }                                                          \
    pc = 0;                                                    \
    dmax = fminf(dmax, dist[KNN - 1]);                         \
    hb = (qd.w - dmax) * 0.5f - 5e-4f;                         \
  } while (0)

// R16 structure (LDS staging, 119->113 us) + PROC diet: the accept test is
// done in DOT space (dot >= hb + 0.5*cw, conservative slack 5e-4 >> fp
// disagreement ~1e-5), 5 VALU/candidate; the EXACT d2 (verified rounding,
// same p0/dot registers) is computed only inside the rare accept branch.
// Extra slack-accepts carry exact d2 and are dropped by INSERT (no-op).
__global__ __launch_bounds__(TPB, 4) void knn_kernel(const float4* __restrict__ cand,
                                                     const float* __restrict__ thr,
                                                     int* __restrict__ knn) {
#pragma clang fp contract(off)
  // 64 KB shared: [0,48K) stacks [SDEPTH][TPB] f2; [48K,64K) staging
  // [8 waves][2 bufs][64] float4. Merge phase reuses [0,40K).
  __shared__ __align__(16) char smem[65536];
  float2* stk = (float2*)smem;

  const int t = threadIdx.x;
  const int lane = t & 63;
  const int wid = t >> 6;                    // wave id == chunk id (QPB==64)
  const int bq = blockIdx.x * QPB + lane;
  const int b = bq >> 13;
  const float4 qd = cand[bq];
  const float4* cb = cand + b * NP;

  float dist[KNN];
  int idx[KNN];
#pragma unroll
  for (int j = 0; j < KNN; ++j) { dist[j] = __builtin_inff(); idx[j] = 0; }
  float dmax = thr[bq];   // conservative seed threshold (>= true 16th distance)
  float hb = (qd.w - dmax) * 0.5f - 5e-4f;
  int pc = 0;

  const int m0 = wid * CHUNK;
  float4* sb = ((float4*)(smem + 49152)) + (size_t)wid * 128;  // [2][64]

  // prologue: group 0 -> buf0; prefetch group 1 into r
  float4 r = cb[m0 + lane];
  sb[lane] = r;
  r = cb[m0 + 64 + lane];
  int p = 0;

#pragma unroll 1
  for (int s = 0; s < CHUNK; s += 64) {
    // drain prior staging write (issued a full group ago -> ~free)
    asm volatile("s_waitcnt lgkmcnt(0)" ::: "memory");
    if (s + 64 < CHUNK) {
      sb[(p ^ 1) * 64 + lane] = r;                 // stage next group
      if (s + 128 < CHUNK) r = cb[m0 + s + 128 + lane];  // prefetch next-next
    }
    const float4* cur = sb + p * 64;
#pragma unroll 1
    for (int g = 0; g < 64; g += 8) {
      float4 c0 = cur[g + 0];
      float4 c1 = cur[g + 1];
      float4 c2 = cur[g + 2];
      float4 c3 = cur[g + 3];
      float4 c4 = cur[g + 4];
      float4 c5 = cur[g + 5];
      float4 c6 = cur[g + 6];
      float4 c7 = cur[g + 7];
#define PROC(cc, mm)                                                \
      do {                                                          \
        float p0 = qd.x * (cc).x;                                   \
        float dot = fmaf(qd.z, (cc).z, fmaf(qd.y, (cc).y, p0));     \
        float hc = fmaf(0.5f, (cc).w, hb);                          \
        if (dot >= hc) { /* conservative dot-space test */          \
          float d2 = fmaf(-2.0f, dot, qd.w + (cc).w); /* exact */   \
          stk[pc * TPB + t] = make_float2(d2, __int_as_float(mm));  \
          ++pc;                                                     \
        }                                                           \
      } while (0)
      PROC(c0, m0 + s + g + 0);
      PROC(c1, m0 + s + g + 1);
      PROC(c2, m0 + s + g + 2);
      PROC(c3, m0 + s + g + 3);
      PROC(c4, m0 + s + g + 4);
      PROC(c5, m0 + s + g + 5);
      PROC(c6, m0 + s + g + 6);
      PROC(c7, m0 + s + g + 7);
#undef PROC
      // post-flush pc==0; check at >=5 leaves pc<=4; +8 -> pc<=12=SDEPTH
      if (__any(pc >= SDEPTH - 7)) FLUSH();
    }
    p ^= 1;
  }
  FLUSH();

  __syncthreads();  // repurpose smem: transposed lists (conflict-free)
  float2* tl = (float2*)smem;               // [KNN][4*QPB] = 32 KB
  float2* al = (float2*)(smem + 32768);     // [KNN][QPB]   =  8 KB

  // ---- phase A: chunks 0..3 publish, 4-way stable merge -> al ----
  if (wid < 4) {
#pragma unroll
    for (int j = 0; j < KNN; ++j)
      tl[j * (4 * QPB) + t] = make_float2(dist[j], __int_as_float(idx[j]));
  }
  __syncthreads();
  if (t < QPB) {
    int p4[4] = {0, 0, 0, 0};
#pragma unroll 1
    for (int j = 0; j < KNN; ++j) {
      float bd = __builtin_inff();
      int bi = 0, bc = 0;
#pragma unroll
      for (int c = 0; c < 4; ++c) {
        bool v = p4[c] < KNN;
        int pp = v ? p4[c] : 0;
        float2 e = tl[pp * (4 * QPB) + t + c * QPB];
        float hd = v ? e.x : __builtin_inff();
        // strict < keeps the earliest chunk on ties (ascending index ranges)
        if (hd < bd || c == 0) { bd = hd; bi = __float_as_int(e.y); bc = c; }
      }
      al[j * QPB + t] = make_float2(bd, __int_as_float(bi));
#pragma unroll
      for (int c = 0; c < 4; ++c) p4[c] += (bc == c);
    }
  }
  __syncthreads();

  // ---- phase B: chunks 4..7 publish (reuse region), 5-way merge -> out ----
  if (wid >= 4) {
#pragma unroll
    for (int j = 0; j < KNN; ++j)
      tl[j * (4 * QPB) + (t - 4 * QPB)] = make_float2(dist[j], __int_as_float(idx[j]));
  }
  __syncthreads();
  if (t < QPB) {
    int p5[5] = {0, 0, 0, 0, 0};  // 0 = al (chunks 0-3), 1..4 = chunks 4..7
    int* kn = knn + bq * KNN;
#pragma unroll 1
    for (int j = 0; j < KNN; ++j) {
      float bd;
      int bi, bc;
      {
        bool v = p5[0] < KNN;
        int pp = v ? p5[0] : 0;
        float2 e = al[pp * QPB + t];
        bd = v ? e.x : __builtin_inff();
        bi = __float_as_int(e.y);
        bc = 0;
      }
#pragma unroll
      for (int c = 0; c < 4; ++c) {
        bool v = p5[c + 1] < KNN;
        int pp = v ? p5[c + 1] : 0;
        float2 e = tl[pp * (4 * QPB) + t + c * QPB];
        float hd = v ? e.x : __builtin_inff();
        if (hd < bd) { bd = hd; bi = __float_as_int(e.y); bc = c + 1; }
      }
      kn[j] = bi;
#pragma unroll
      for (int c = 0; c < 5; ++c) p5[c] += (bc == c);
    }
  }
}

__global__ void walk_kernel(const int* __restrict__ rand_k, const int* __restrict__ knn,
                            int* __restrict__ out) {
  int t = blockIdx.x * blockDim.x + threadIdx.x;
  if (t >= NB * NP) return;
  int b = t >> 13;
  int n = t & (NP - 1);
  int cur = n;
  int* o = out + t * CLEN;
  o[0] = cur;
#pragma unroll
  for (int l = 0; l < CLEN - 1; ++l) {
    int rk = rand_k[(l * NB + b) * NP + n];
    cur = knn[(b * NP + cur) * KNN + rk];
    o[l + 1] = cur;
  }
}

extern "C" void kernel_launch(void* const* d_in, const int* in_sizes, int n_in,
                              void* d_out, int out_size, void* d_ws, size_t ws_size,
                              hipStream_t stream) {
  const float* xyz = (const float*)d_in[0];
  const int* rand_k = (const int*)d_in[1];
  int* out = (int*)d_out;

  char* w = (char*)d_ws;
  float4* cand  = (float4*)(w);                       // 512 KB natural order
  float4* scand = (float4*)(w + 524288);              // 512 KB Morton-sorted
  int* sidx     = (int*)(w + 1048576);                // 128 KB
  float* thr    = (float*)(w + 1179648);              // 128 KB
  int* knnt     = (int*)(w + 1310720);                // 2 MB
  int* cellid   = (int*)(w + 3407872);                // 128 KB
  int* hist     = (int*)(w + 3538944);                // 64 KB
  int* cursor   = (int*)(w + 3604480);                // 64 KB (adjacent)
  int* offs     = (int*)(w + 3670016);                // 64 KB

  hipMemsetAsync(hist, 0, 131072, stream);  // hist + cursor

  bin_kernel<<<(NB * NP + 255) / 256, 256, 0, stream>>>(xyz, cellid, hist);
  scan_kernel<<<NB, 1024, 0, stream>>>(hist, offs);
  scatter_kernel<<<(NB * NP + 255) / 256, 256, 0, stream>>>(xyz, cellid, offs, cursor,
                                                            scand, sidx, cand);
  thresh_kernel<<<(NB * NP + 255) / 256, 256, 0, stream>>>(scand, sidx, thr);
  knn_kernel<<<(NB * NP) / QPB, TPB, 0, stream>>>(cand, thr, knnt);
  walk_kernel<<<(NB * NP + 255) / 256, 256, 0, stream>>>(rand_k, knnt, out);
}